// Round 4
// baseline (1293.189 us; speedup 1.0000x reference)
//
#include <hip/hip_runtime.h>
#include <hip/hip_fp16.h>

#define NN 100000
#define NE 1600000
#define FD 128
#define OS 512   // output row stride: [feat | h1 | h2 | h3]
#define LDA 136  // LDS row stride in bf16 elems (128 + 8 pad -> bank-conflict-free)
#define NBKT 196 // dst buckets of 512 nodes: (99999>>9)=195 -> 196 buckets
#define PCH 4096 // edges per block in partition pass
#define NSL 8    // feature slices of 16 cols: slice = NN*16 fp16 = 3.2 MB (fits XCD L2)
#define NBG 3128 // 32-node groups per slice pass; 3128*32 >= NN, and %8==0 so the
                 // node-group -> XCD mapping is slice-invariant (col stays L2-hot)

typedef __attribute__((ext_vector_type(8))) short short8;
typedef __attribute__((ext_vector_type(4))) float f32x4;

__device__ __forceinline__ short f2bf(float x) {
    unsigned u = __float_as_uint(x);
    u = (u + 0x7fff + ((u >> 16) & 1)) >> 16;   // round-to-nearest-even
    return (short)u;
}

// ---------------- init: copy feat into cols 0:128 of out ----------------
__global__ void k_init_out(const float* __restrict__ feat, float* __restrict__ out) {
    const size_t total = (size_t)NN * 32;  // float4s per feat row
    for (size_t i = (size_t)blockIdx.x * blockDim.x + threadIdx.x; i < total;
         i += (size_t)gridDim.x * blockDim.x) {
        size_t n = i >> 5;
        int c4 = (int)(i & 31);
        ((float4*)(out + n * OS))[c4] = ((const float4*)feat)[n * 32 + c4];
    }
}

// ---------------- prep: Wt[l][n][k] = bf16(W_l[k][n]) ----------------
__global__ void k_prep_w(const float* __restrict__ W0, const float* __restrict__ W1,
                         const float* __restrict__ W2, short* __restrict__ Wt) {
    int i = blockIdx.x * blockDim.x + threadIdx.x;
    if (i >= 3 * FD * FD) return;
    int l = i >> 14, r = i & (FD * FD - 1);
    int n = r >> 7, k = r & 127;
    const float* W = (l == 0) ? W0 : ((l == 1) ? W1 : W2);
    Wt[i] = f2bf(W[k * FD + n]);   // i = l*16384 + n*128 + k
}

// ---------------- degree histogram (int atomics, int4 edge loads) ----------------
__global__ void k_degrees(const int* __restrict__ src, const int* __restrict__ dst,
                          int* __restrict__ cnt_out, int* __restrict__ cnt_in) {
    const int total4 = NE / 4;
    for (int i = blockIdx.x * blockDim.x + threadIdx.x; i < total4;
         i += gridDim.x * blockDim.x) {
        int4 s = ((const int4*)src)[i];
        int4 d = ((const int4*)dst)[i];
        atomicAdd(&cnt_out[s.x], 1); atomicAdd(&cnt_out[s.y], 1);
        atomicAdd(&cnt_out[s.z], 1); atomicAdd(&cnt_out[s.w], 1);
        atomicAdd(&cnt_in[d.x], 1); atomicAdd(&cnt_in[d.y], 1);
        atomicAdd(&cnt_in[d.z], 1); atomicAdd(&cnt_in[d.w], 1);
    }
}

__global__ void k_invsqrt(const int* __restrict__ cnt, float* __restrict__ inv, int n) {
    int i = blockIdx.x * blockDim.x + threadIdx.x;
    if (i < n) inv[i] = rsqrtf((float)max(cnt[i], 1));
}

// ---------------- single-block scan, 4 elems/thread ----------------
__global__ __launch_bounds__(1024) void k_scan(const int* __restrict__ cnt_in,
                                               int* __restrict__ row_ptr,
                                               int* __restrict__ cursor) {
    __shared__ int wsum[16];
    __shared__ int wscan[16];
    __shared__ int carry_s;
    const int tid = threadIdx.x;
    const int lane = tid & 63;
    const int wid = tid >> 6;
    if (tid == 0) carry_s = 0;
    __syncthreads();
    for (int base = 0; base < NN; base += 4096) {
        const int i0 = base + tid * 4;
        int4 v = make_int4(0, 0, 0, 0);
        if (i0 + 3 < NN) {
            v = ((const int4*)(cnt_in + base))[tid];
        } else {
            if (i0 < NN) v.x = cnt_in[i0];
            if (i0 + 1 < NN) v.y = cnt_in[i0 + 1];
            if (i0 + 2 < NN) v.z = cnt_in[i0 + 2];
            if (i0 + 3 < NN) v.w = cnt_in[i0 + 3];
        }
        const int s = v.x + v.y + v.z + v.w;
        int incl = s;
        #pragma unroll
        for (int off = 1; off < 64; off <<= 1) {
            int t = __shfl_up(incl, off, 64);
            if (lane >= off) incl += t;
        }
        if (lane == 63) wsum[wid] = incl;
        __syncthreads();
        if (wid == 0) {
            int t = (lane < 16) ? wsum[lane] : 0;
            #pragma unroll
            for (int off = 1; off < 16; off <<= 1) {
                int u = __shfl_up(t, off, 64);
                if (lane >= off) t += u;
            }
            if (lane < 16) wscan[lane] = t;
        }
        __syncthreads();
        const int wbase = (wid > 0) ? wscan[wid - 1] : 0;
        int p = carry_s + wbase + incl - s;
        if (i0 < NN) { row_ptr[i0] = p; cursor[i0] = p; }
        if (i0 + 1 < NN) { row_ptr[i0 + 1] = p + v.x; cursor[i0 + 1] = p + v.x; }
        if (i0 + 2 < NN) { row_ptr[i0 + 2] = p + v.x + v.y; cursor[i0 + 2] = p + v.x + v.y; }
        if (i0 + 3 < NN) { row_ptr[i0 + 3] = p + v.x + v.y + v.z; cursor[i0 + 3] = p + v.x + v.y + v.z; }
        __syncthreads();
        if (tid == 0) carry_s += wscan[15];
        __syncthreads();
    }
    if (tid == 0) row_ptr[NN] = carry_s;
}

// ---------------- bucket cursors: bkt[b] = row_ptr[b<<9] ----------------
__global__ void k_bkt_init(const int* __restrict__ row_ptr, int* __restrict__ bkt) {
    int b = blockIdx.x * blockDim.x + threadIdx.x;
    if (b < NBKT) bkt[b] = row_ptr[min(b << 9, NN)];
}

// ---------------- P1: radix-partition edges into dst-buckets (pairs) ----------
__global__ __launch_bounds__(256) void k_part(const int* __restrict__ src,
                                              const int* __restrict__ dst,
                                              int* __restrict__ bkt_cursor,
                                              int2* __restrict__ pairs) {
    __shared__ int hist[NBKT];
    __shared__ int base[NBKT];
    __shared__ int lofs[NBKT];
    const int tid = threadIdx.x;
    const int e0 = blockIdx.x * PCH;
    for (int i = tid; i < NBKT; i += 256) { hist[i] = 0; lofs[i] = 0; }
    __syncthreads();
    int md[16], ms[16];
    #pragma unroll
    for (int k = 0; k < 16; ++k) {
        int e = e0 + k * 256 + tid;
        md[k] = (e < NE) ? dst[e] : -1;
        ms[k] = (e < NE) ? src[e] : 0;
    }
    #pragma unroll
    for (int k = 0; k < 16; ++k)
        if (md[k] >= 0) atomicAdd(&hist[md[k] >> 9], 1);
    __syncthreads();
    for (int i = tid; i < NBKT; i += 256)
        base[i] = hist[i] ? atomicAdd(&bkt_cursor[i], hist[i]) : 0;
    __syncthreads();
    #pragma unroll
    for (int k = 0; k < 16; ++k)
        if (md[k] >= 0) {
            int b = md[k] >> 9;
            int off = atomicAdd(&lofs[b], 1);
            pairs[base[b] + off] = make_int2(ms[k], md[k]);
        }
}

// ---------------- P2: CSR fill from bucket-sorted pairs ----------------
__global__ __launch_bounds__(256) void k_fill2(const int2* __restrict__ pairs,
                                               int* __restrict__ cursor,
                                               int* __restrict__ col, int nblk) {
    // bijective chunked swizzle (m204): consecutive logical chunks -> same XCD
    const int bid = blockIdx.x;
    const int q = nblk >> 3, r = nblk & 7;
    const int xcd = bid & 7, idx = bid >> 3;
    const int logical = (xcd < r ? xcd * (q + 1) : r * (q + 1) + (xcd - r) * q) + idx;
    const int e0 = logical * 1024;
    #pragma unroll
    for (int k = 0; k < 4; ++k) {
        int e = e0 + k * 256 + threadIdx.x;
        if (e < NE) {
            int2 p = pairs[e];
            int pos = atomicAdd(&cursor[p.y], 1);
            col[pos] = p.x;
        }
    }
}

// ---------------- MFMA GEMM: tmp (slice-major) = fp16(inv_out[r]*(bf16(h)@bf16(W)))
// tmp layout: [NSL][NN][16] fp16 -> each 16-col slice is 3.2 MB (XCD-L2-resident
// for the gather). ct IS the slice index in the epilogue.
__global__ __launch_bounds__(256) void k_gemm(const float* __restrict__ h, int hstride,
                                              const short* __restrict__ Wt,
                                              const float* __restrict__ inv_out,
                                              __half* __restrict__ tmp) {
    __shared__ short Ws[FD * LDA];   // Wt[n][k], padded rows: 34 KB
    __shared__ short hA[64 * LDA];   // h tile bf16, padded rows: 17 KB
    const int tid = threadIdx.x;
    for (int i = tid; i < FD * 16; i += 256) {   // 2048 chunks of 8 bf16
        int n = i >> 4, c = i & 15;
        short8 v = *(const short8*)(Wt + n * FD + c * 8);
        *(short8*)(&Ws[n * LDA + c * 8]) = v;
    }
    const int row0 = blockIdx.x * 128;
    const int wid = tid >> 6, lane = tid & 63;
    const int m = lane & 15, quad = lane >> 4;

    for (int sub = 0; sub < 2; ++sub) {
        const int rbase = row0 + sub * 64;
        __syncthreads();   // sub0: Ws staged; sub>0: prev compute done before hA overwrite
        for (int i = tid; i < 64 * 32; i += 256) {   // float4 chunks
            int r = i >> 5, c4 = i & 31;
            int gr = rbase + r;
            float4 v = make_float4(0.f, 0.f, 0.f, 0.f);
            if (gr < NN) v = ((const float4*)(h + (size_t)gr * hstride))[c4];
            short4 b;
            b.x = f2bf(v.x); b.y = f2bf(v.y); b.z = f2bf(v.z); b.w = f2bf(v.w);
            *(short4*)(&hA[r * LDA + c4 * 4]) = b;
        }
        __syncthreads();
        const int rtile = rbase + wid * 16;          // this wave's 16 rows
        short8 a0 = *(const short8*)(&hA[(wid * 16 + m) * LDA + 0 * 32 + quad * 8]);
        short8 a1 = *(const short8*)(&hA[(wid * 16 + m) * LDA + 1 * 32 + quad * 8]);
        short8 a2 = *(const short8*)(&hA[(wid * 16 + m) * LDA + 2 * 32 + quad * 8]);
        short8 a3 = *(const short8*)(&hA[(wid * 16 + m) * LDA + 3 * 32 + quad * 8]);
        float s0, s1, s2, s3;
        {
            int r = rtile + quad * 4;
            s0 = (r + 0 < NN) ? inv_out[r + 0] : 0.f;
            s1 = (r + 1 < NN) ? inv_out[r + 1] : 0.f;
            s2 = (r + 2 < NN) ? inv_out[r + 2] : 0.f;
            s3 = (r + 3 < NN) ? inv_out[r + 3] : 0.f;
        }
        #pragma unroll
        for (int ct = 0; ct < 8; ++ct) {
            f32x4 acc = {0.f, 0.f, 0.f, 0.f};
            short8 b0 = *(const short8*)(&Ws[(ct * 16 + m) * LDA + 0 * 32 + quad * 8]);
            short8 b1 = *(const short8*)(&Ws[(ct * 16 + m) * LDA + 1 * 32 + quad * 8]);
            short8 b2 = *(const short8*)(&Ws[(ct * 16 + m) * LDA + 2 * 32 + quad * 8]);
            short8 b3 = *(const short8*)(&Ws[(ct * 16 + m) * LDA + 3 * 32 + quad * 8]);
            acc = __builtin_amdgcn_mfma_f32_16x16x32_bf16(a0, b0, acc, 0, 0, 0);
            acc = __builtin_amdgcn_mfma_f32_16x16x32_bf16(a1, b1, acc, 0, 0, 0);
            acc = __builtin_amdgcn_mfma_f32_16x16x32_bf16(a2, b2, acc, 0, 0, 0);
            acc = __builtin_amdgcn_mfma_f32_16x16x32_bf16(a3, b3, acc, 0, 0, 0);
            // slice-major store: tmp[ct][r][m]
            const int r = rtile + quad * 4;
            __half* ts = tmp + (size_t)ct * NN * 16 + m;
            if (r + 3 < NN) {
                ts[(size_t)(r + 0) * 16] = __float2half_rn(acc[0] * s0);
                ts[(size_t)(r + 1) * 16] = __float2half_rn(acc[1] * s1);
                ts[(size_t)(r + 2) * 16] = __float2half_rn(acc[2] * s2);
                ts[(size_t)(r + 3) * 16] = __float2half_rn(acc[3] * s3);
            } else {
                if (r + 0 < NN) ts[(size_t)(r + 0) * 16] = __float2half_rn(acc[0] * s0);
                if (r + 1 < NN) ts[(size_t)(r + 1) * 16] = __float2half_rn(acc[1] * s1);
                if (r + 2 < NN) ts[(size_t)(r + 2) * 16] = __float2half_rn(acc[2] * s2);
                if (r + 3 < NN) ts[(size_t)(r + 3) * 16] = __float2half_rn(acc[3] * s3);
            }
        }
    }
}

// ---------------- gather, slice-passes: out[d][off+s*16:+16] += ... ----------
// Grid = NSL * NBG blocks, slice-major dispatch: at any instant ~one 3.2 MB
// slice is hot -> replicated in every XCD L2, random row reads become L2 hits
// (old scheme: 256 B random rows from 25.6 MB = L3-transaction-bound ~2.7 TB/s).
// Wave = 1 node at a time (8 nodes serially); 8-lane groups own one edge each
// (32 B of the slice row), x2 unroll -> 16 edges in flight; 3-step shfl fold.
__global__ __launch_bounds__(256) void k_gather(const __half* __restrict__ tmp,
                                                const int* __restrict__ row_ptr,
                                                const int* __restrict__ col,
                                                const float* __restrict__ inv_in,
                                                const float* __restrict__ b,
                                                float* __restrict__ out, int off) {
    const int bid = blockIdx.x;
    const int s = bid / NBG;              // slice (dispatch order: slice-major)
    const int nb = bid - s * NBG;
    const int wid = threadIdx.x >> 6;
    const int lane = threadIdx.x & 63;
    const int g = lane >> 3;              // edge slot 0..7
    const int p = lane & 7;               // __half2 chunk within 16-col slice
    const __half2* t2 = (const __half2*)(tmp + (size_t)s * NN * 16);
    const float2 bb = ((const float2*)(b + s * 16))[p];
    const int n0 = nb * 32 + wid * 8;
    for (int i = 0; i < 8; ++i) {
        const int node = n0 + i;
        if (node >= NN) return;           // only tail blocks hit this
        const int beg = row_ptr[node], end = row_ptr[node + 1];
        float2 a0 = make_float2(0.f, 0.f), a1 = make_float2(0.f, 0.f);
        for (int j0 = beg; j0 < end; j0 += 16) {
            int ja = j0 + g, jb = j0 + 8 + g;
            if (ja < end) {
                float2 f = __half22float2(t2[(size_t)col[ja] * 8 + p]);
                a0.x += f.x; a0.y += f.y;
            }
            if (jb < end) {
                float2 f = __half22float2(t2[(size_t)col[jb] * 8 + p]);
                a1.x += f.x; a1.y += f.y;
            }
        }
        a0.x += a1.x; a0.y += a1.y;
        a0.x += __shfl_xor(a0.x, 8);  a0.y += __shfl_xor(a0.y, 8);
        a0.x += __shfl_xor(a0.x, 16); a0.y += __shfl_xor(a0.y, 16);
        a0.x += __shfl_xor(a0.x, 32); a0.y += __shfl_xor(a0.y, 32);
        if (g == 0) {
            const float sc = inv_in[node];
            float2 r;
            r.x = fmaxf(a0.x * sc + bb.x, 0.f);
            r.y = fmaxf(a0.y * sc + bb.y, 0.f);
            ((float2*)(out + (size_t)node * OS + off + s * 16))[p] = r;
        }
    }
}

extern "C" void kernel_launch(void* const* d_in, const int* in_sizes, int n_in,
                              void* d_out, int out_size, void* d_ws, size_t ws_size,
                              hipStream_t stream) {
    const float* feat = (const float*)d_in[0];
    const float* W0 = (const float*)d_in[1];
    const float* b0 = (const float*)d_in[2];
    const float* W1 = (const float*)d_in[3];
    const float* b1 = (const float*)d_in[4];
    const float* W2 = (const float*)d_in[5];
    const float* b2 = (const float*)d_in[6];
    const int* src = (const int*)d_in[7];
    const int* dst = (const int*)d_in[8];
    float* out = (float*)d_out;
    float* ws = (float*)d_ws;

    __half* tmp = (__half*)ws;                // NSL*NN*16 halves = 25.6MB (slice-major)
    int2* pairs = (int2*)(ws + (size_t)NN * 64);  // 12.8MB in the free upper half of tmp region
    int* cnt = (int*)(ws + (size_t)NN * FD);  // 2N ints (cnt_out | cnt_in)
    float* inv = (float*)(cnt + 2 * NN);      // 2N floats (inv_out | inv_in)
    int* row_ptr = (int*)(inv + 2 * NN);      // N+1 ints
    int* cursor = row_ptr + NN + 1;           // N ints
    int* col = cursor + NN;                   // NE ints
    short* Wt = (short*)(col + NE);           // 3*FD*FD bf16
    int* bkt = (int*)(Wt + 3 * FD * FD);      // NBKT ints

    hipMemsetAsync(cnt, 0, 2 * NN * sizeof(int), stream);
    k_init_out<<<4096, 256, 0, stream>>>(feat, out);
    k_prep_w<<<(3 * FD * FD + 255) / 256, 256, 0, stream>>>(W0, W1, W2, Wt);
    k_degrees<<<2048, 256, 0, stream>>>(src, dst, cnt, cnt + NN);
    k_invsqrt<<<(2 * NN + 255) / 256, 256, 0, stream>>>(cnt, inv, 2 * NN);
    k_scan<<<1, 1024, 0, stream>>>(cnt + NN, row_ptr, cursor);
    k_bkt_init<<<1, 256, 0, stream>>>(row_ptr, bkt);
    k_part<<<(NE + PCH - 1) / PCH, 256, 0, stream>>>(src, dst, bkt, pairs);
    {
        const int nblk = (NE + 1023) / 1024;
        k_fill2<<<nblk, 256, 0, stream>>>(pairs, cursor, col, nblk);
    }

    const float* bs[3] = {b0, b1, b2};
    const float* h = feat;
    int hstride = FD;
    for (int l = 0; l < 3; ++l) {
        k_gemm<<<(NN + 127) / 128, 256, 0, stream>>>(h, hstride, Wt + l * FD * FD, inv, tmp);
        k_gather<<<NSL * NBG, 256, 0, stream>>>(tmp, row_ptr, col, inv + NN, bs[l], out,
                                                FD * (l + 1));
        h = out + FD * (l + 1);
        hstride = OS;
    }
}

// Round 5
// 669.326 us; speedup vs baseline: 1.9321x; 1.9321x over previous
//
#include <hip/hip_runtime.h>
#include <hip/hip_fp16.h>

#define NN 100000
#define NE 1600000
#define FD 128
#define OS 512   // output row stride: [feat | h1 | h2 | h3]
#define LDA 136  // LDS row stride in bf16 elems (128 + 8 pad -> bank-conflict-free)
#define NBKT 196 // dst buckets of 512 nodes: (99999>>9)=195 -> 196 buckets
#define PCH 4096 // edges per block in partition pass

typedef __attribute__((ext_vector_type(8))) short short8;
typedef __attribute__((ext_vector_type(4))) float f32x4;

struct h4v { __half2 lo, hi; };   // 8 B = 4 halves

__device__ __forceinline__ short f2bf(float x) {
    unsigned u = __float_as_uint(x);
    u = (u + 0x7fff + ((u >> 16) & 1)) >> 16;   // round-to-nearest-even
    return (short)u;
}

// ---------------- init: copy feat into cols 0:128 of out ----------------
__global__ void k_init_out(const float* __restrict__ feat, float* __restrict__ out) {
    const size_t total = (size_t)NN * 32;  // float4s per feat row
    for (size_t i = (size_t)blockIdx.x * blockDim.x + threadIdx.x; i < total;
         i += (size_t)gridDim.x * blockDim.x) {
        size_t n = i >> 5;
        int c4 = (int)(i & 31);
        ((float4*)(out + n * OS))[c4] = ((const float4*)feat)[n * 32 + c4];
    }
}

// ---------------- prep: Wt[l][n][k] = bf16(W_l[k][n]) ----------------
__global__ void k_prep_w(const float* __restrict__ W0, const float* __restrict__ W1,
                         const float* __restrict__ W2, short* __restrict__ Wt) {
    int i = blockIdx.x * blockDim.x + threadIdx.x;
    if (i >= 3 * FD * FD) return;
    int l = i >> 14, r = i & (FD * FD - 1);
    int n = r >> 7, k = r & 127;
    const float* W = (l == 0) ? W0 : ((l == 1) ? W1 : W2);
    Wt[i] = f2bf(W[k * FD + n]);   // i = l*16384 + n*128 + k
}

// ---------------- degrees: out-degree atomics + dst-BUCKET histogram ----------
// (per-node in-degrees are derived later per-bucket in k_build; this halves the
// random global atomic traffic of the old k_degrees)
__global__ __launch_bounds__(256) void k_deg(const int* __restrict__ src,
                                             const int* __restrict__ dst,
                                             int* __restrict__ cnt_out,
                                             int* __restrict__ bktcnt) {
    __shared__ int h[NBKT];
    for (int i = threadIdx.x; i < NBKT; i += 256) h[i] = 0;
    __syncthreads();
    const int total4 = NE / 4;
    for (int i = blockIdx.x * blockDim.x + threadIdx.x; i < total4;
         i += gridDim.x * blockDim.x) {
        int4 s = ((const int4*)src)[i];
        int4 d = ((const int4*)dst)[i];
        atomicAdd(&cnt_out[s.x], 1); atomicAdd(&cnt_out[s.y], 1);
        atomicAdd(&cnt_out[s.z], 1); atomicAdd(&cnt_out[s.w], 1);
        atomicAdd(&h[d.x >> 9], 1); atomicAdd(&h[d.y >> 9], 1);
        atomicAdd(&h[d.z >> 9], 1); atomicAdd(&h[d.w >> 9], 1);
    }
    __syncthreads();
    for (int i = threadIdx.x; i < NBKT; i += 256)
        if (h[i]) atomicAdd(&bktcnt[i], h[i]);
}

__global__ void k_invsqrt(const int* __restrict__ cnt, float* __restrict__ inv, int n) {
    int i = blockIdx.x * blockDim.x + threadIdx.x;
    if (i < n) inv[i] = rsqrtf((float)max(cnt[i], 1));
}

// ---------------- scan of 196 bucket counts (1 block) ----------------
__global__ __launch_bounds__(256) void k_bkt_scan(const int* __restrict__ bktcnt,
                                                  int* __restrict__ bkt_base,
                                                  int* __restrict__ bkt_cursor) {
    __shared__ int s[256];
    const int tid = threadIdx.x;
    int v = (tid < NBKT) ? bktcnt[tid] : 0;
    s[tid] = v;
    __syncthreads();
    for (int off = 1; off < 256; off <<= 1) {
        int t = (tid >= off) ? s[tid - off] : 0;
        __syncthreads();
        s[tid] += t;
        __syncthreads();
    }
    int excl = s[tid] - v;
    if (tid < NBKT) { bkt_base[tid] = excl; bkt_cursor[tid] = excl; }
    if (tid == NBKT - 1) bkt_base[NBKT] = excl + v;   // == NE
}

// ---------------- P1: radix-partition edges into dst-buckets (pairs) ----------
__global__ __launch_bounds__(256) void k_part(const int* __restrict__ src,
                                              const int* __restrict__ dst,
                                              int* __restrict__ bkt_cursor,
                                              int2* __restrict__ pairs) {
    __shared__ int hist[NBKT];
    __shared__ int base[NBKT];
    __shared__ int lofs[NBKT];
    const int tid = threadIdx.x;
    const int e0 = blockIdx.x * PCH;
    for (int i = tid; i < NBKT; i += 256) { hist[i] = 0; lofs[i] = 0; }
    __syncthreads();
    int md[16], ms[16];
    #pragma unroll
    for (int k = 0; k < 16; ++k) {
        int e = e0 + k * 256 + tid;
        md[k] = (e < NE) ? dst[e] : -1;
        ms[k] = (e < NE) ? src[e] : 0;
    }
    #pragma unroll
    for (int k = 0; k < 16; ++k)
        if (md[k] >= 0) atomicAdd(&hist[md[k] >> 9], 1);
    __syncthreads();
    for (int i = tid; i < NBKT; i += 256)
        base[i] = hist[i] ? atomicAdd(&bkt_cursor[i], hist[i]) : 0;
    __syncthreads();
    #pragma unroll
    for (int k = 0; k < 16; ++k)
        if (md[k] >= 0) {
            int b = md[k] >> 9;
            int off = atomicAdd(&lofs[b], 1);
            pairs[base[b] + off] = make_int2(ms[k], md[k]);
        }
}

// ---------------- P2: per-bucket CSR build (replaces scan + fill2) ----------
// One block per bucket: LDS histogram of the 512 local nodes -> LDS scan ->
// row_ptr + inv_in writes, then LDS-cursor placement of col. pairs are L3-hot
// (just written by k_part); all atomics are LDS.
__global__ __launch_bounds__(256) void k_build(const int2* __restrict__ pairs,
                                               const int* __restrict__ bkt_base,
                                               int* __restrict__ row_ptr,
                                               int* __restrict__ col,
                                               float* __restrict__ inv_in) {
    __shared__ int cnt_s[512];
    __shared__ int wsum[4];
    const int b = blockIdx.x;
    const int tid = threadIdx.x;
    const int lane = tid & 63, wid = tid >> 6;
    const int ebeg = bkt_base[b], eend = bkt_base[b + 1];
    const int n0 = b << 9;
    cnt_s[tid] = 0; cnt_s[tid + 256] = 0;
    __syncthreads();
    for (int e = ebeg + tid; e < eend; e += 256)
        atomicAdd(&cnt_s[pairs[e].y - n0], 1);
    __syncthreads();
    // exclusive scan of 512 counters (2 per thread)
    const int v0 = cnt_s[2 * tid], v1 = cnt_s[2 * tid + 1];
    const int sum2 = v0 + v1;
    int incl = sum2;
    #pragma unroll
    for (int off = 1; off < 64; off <<= 1) {
        int t = __shfl_up(incl, off, 64);
        if (lane >= off) incl += t;
    }
    if (lane == 63) wsum[wid] = incl;
    __syncthreads();
    if (tid == 0) {
        int c = 0;
        #pragma unroll
        for (int i = 0; i < 4; ++i) { int t = wsum[i]; wsum[i] = c; c += t; }
    }
    __syncthreads();
    const int e0 = wsum[wid] + incl - sum2;   // exclusive offset of elem 2*tid
    cnt_s[2 * tid] = e0;                      // reuse as local cursors
    cnt_s[2 * tid + 1] = e0 + v0;
    const int g0 = n0 + 2 * tid, g1 = g0 + 1;
    if (g0 < NN) { row_ptr[g0] = ebeg + e0; inv_in[g0] = rsqrtf((float)max(v0, 1)); }
    if (g1 < NN) { row_ptr[g1] = ebeg + e0 + v0; inv_in[g1] = rsqrtf((float)max(v1, 1)); }
    if (b == NBKT - 1 && tid == 0) row_ptr[NN] = eend;
    __syncthreads();
    for (int e = ebeg + tid; e < eend; e += 256) {
        int2 p = pairs[e];
        int pos = atomicAdd(&cnt_s[p.y - n0], 1);
        col[ebeg + pos] = p.x;
    }
}

// ---------------- MFMA GEMM: tmp[r][:] = fp16(inv_out[r] * (bf16(h[r][:]) @ bf16(W)))
__global__ __launch_bounds__(256) void k_gemm(const float* __restrict__ h, int hstride,
                                              const short* __restrict__ Wt,
                                              const float* __restrict__ inv_out,
                                              __half* __restrict__ tmp) {
    __shared__ short Ws[FD * LDA];   // Wt[n][k], padded rows: 34 KB
    __shared__ short hA[64 * LDA];   // h tile bf16, padded rows: 17 KB
    const int tid = threadIdx.x;
    for (int i = tid; i < FD * 16; i += 256) {   // 2048 chunks of 8 bf16
        int n = i >> 4, c = i & 15;
        short8 v = *(const short8*)(Wt + n * FD + c * 8);
        *(short8*)(&Ws[n * LDA + c * 8]) = v;
    }
    const int row0 = blockIdx.x * 128;
    const int wid = tid >> 6, lane = tid & 63;
    const int m = lane & 15, quad = lane >> 4;

    for (int sub = 0; sub < 2; ++sub) {
        const int rbase = row0 + sub * 64;
        __syncthreads();   // sub0: Ws staged; sub>0: prev compute done before hA overwrite
        for (int i = tid; i < 64 * 32; i += 256) {   // float4 chunks
            int r = i >> 5, c4 = i & 31;
            int gr = rbase + r;
            float4 v = make_float4(0.f, 0.f, 0.f, 0.f);
            if (gr < NN) v = ((const float4*)(h + (size_t)gr * hstride))[c4];
            short4 b;
            b.x = f2bf(v.x); b.y = f2bf(v.y); b.z = f2bf(v.z); b.w = f2bf(v.w);
            *(short4*)(&hA[r * LDA + c4 * 4]) = b;
        }
        __syncthreads();
        const int rtile = rbase + wid * 16;          // this wave's 16 rows
        short8 a0 = *(const short8*)(&hA[(wid * 16 + m) * LDA + 0 * 32 + quad * 8]);
        short8 a1 = *(const short8*)(&hA[(wid * 16 + m) * LDA + 1 * 32 + quad * 8]);
        short8 a2 = *(const short8*)(&hA[(wid * 16 + m) * LDA + 2 * 32 + quad * 8]);
        short8 a3 = *(const short8*)(&hA[(wid * 16 + m) * LDA + 3 * 32 + quad * 8]);
        float s0, s1, s2, s3;
        {
            int r = rtile + quad * 4;
            s0 = (r + 0 < NN) ? inv_out[r + 0] : 0.f;
            s1 = (r + 1 < NN) ? inv_out[r + 1] : 0.f;
            s2 = (r + 2 < NN) ? inv_out[r + 2] : 0.f;
            s3 = (r + 3 < NN) ? inv_out[r + 3] : 0.f;
        }
        #pragma unroll
        for (int ct = 0; ct < 8; ++ct) {
            f32x4 acc = {0.f, 0.f, 0.f, 0.f};
            short8 b0 = *(const short8*)(&Ws[(ct * 16 + m) * LDA + 0 * 32 + quad * 8]);
            short8 b1 = *(const short8*)(&Ws[(ct * 16 + m) * LDA + 1 * 32 + quad * 8]);
            short8 b2 = *(const short8*)(&Ws[(ct * 16 + m) * LDA + 2 * 32 + quad * 8]);
            short8 b3 = *(const short8*)(&Ws[(ct * 16 + m) * LDA + 3 * 32 + quad * 8]);
            acc = __builtin_amdgcn_mfma_f32_16x16x32_bf16(a0, b0, acc, 0, 0, 0);
            acc = __builtin_amdgcn_mfma_f32_16x16x32_bf16(a1, b1, acc, 0, 0, 0);
            acc = __builtin_amdgcn_mfma_f32_16x16x32_bf16(a2, b2, acc, 0, 0, 0);
            acc = __builtin_amdgcn_mfma_f32_16x16x32_bf16(a3, b3, acc, 0, 0, 0);
            const int r = rtile + quad * 4;
            const int c = ct * 16 + m;
            if (r + 3 < NN) {
                tmp[(size_t)(r + 0) * FD + c] = __float2half_rn(acc[0] * s0);
                tmp[(size_t)(r + 1) * FD + c] = __float2half_rn(acc[1] * s1);
                tmp[(size_t)(r + 2) * FD + c] = __float2half_rn(acc[2] * s2);
                tmp[(size_t)(r + 3) * FD + c] = __float2half_rn(acc[3] * s3);
            } else {
                if (r + 0 < NN) tmp[(size_t)(r + 0) * FD + c] = __float2half_rn(acc[0] * s0);
                if (r + 1 < NN) tmp[(size_t)(r + 1) * FD + c] = __float2half_rn(acc[1] * s1);
                if (r + 2 < NN) tmp[(size_t)(r + 2) * FD + c] = __float2half_rn(acc[2] * s2);
                if (r + 3 < NN) tmp[(size_t)(r + 3) * FD + c] = __float2half_rn(acc[3] * s3);
            }
        }
    }
}

// ---------------- gather: out[d][off:off+128] = relu(inv_in[d]*sum tmp[s] + b) ----
// (round-3 form: row-major 256 B fp16 rows, 32-lane half-waves, 8 edges in flight)
__global__ __launch_bounds__(256) void k_gather(const __half* __restrict__ tmp,
                                                const int* __restrict__ row_ptr,
                                                const int* __restrict__ col,
                                                const float* __restrict__ inv_in,
                                                const float* __restrict__ b,
                                                float* __restrict__ out, int off) {
    const int wid = threadIdx.x >> 6;
    const int lane = threadIdx.x & 63;
    const int half = lane >> 5;   // 0: even edges, 1: odd edges
    const int sl = lane & 31;     // position within the 256 B row (8 B per lane)
    const int node = blockIdx.x * 4 + wid;
    if (node >= NN) return;
    const int beg = row_ptr[node], end = row_ptr[node + 1];
    const h4v* t4 = (const h4v*)tmp;   // row = 32 h4v units
    float4 acc = make_float4(0.f, 0.f, 0.f, 0.f);
    int j = beg + half;
    for (; j + 6 < end; j += 8) {   // 4 edges per half per iter -> 8/wave in flight
        int s0 = col[j], s1 = col[j + 2], s2 = col[j + 4], s3 = col[j + 6];
        h4v v0 = t4[(size_t)s0 * 32 + sl];
        h4v v1 = t4[(size_t)s1 * 32 + sl];
        h4v v2 = t4[(size_t)s2 * 32 + sl];
        h4v v3 = t4[(size_t)s3 * 32 + sl];
        float2 l0 = __half22float2(v0.lo), h0 = __half22float2(v0.hi);
        float2 l1 = __half22float2(v1.lo), h1 = __half22float2(v1.hi);
        float2 l2 = __half22float2(v2.lo), h2 = __half22float2(v2.hi);
        float2 l3 = __half22float2(v3.lo), h3 = __half22float2(v3.hi);
        acc.x += (l0.x + l1.x) + (l2.x + l3.x);
        acc.y += (l0.y + l1.y) + (l2.y + l3.y);
        acc.z += (h0.x + h1.x) + (h2.x + h3.x);
        acc.w += (h0.y + h1.y) + (h2.y + h3.y);
    }
    for (; j < end; j += 2) {
        h4v v = t4[(size_t)col[j] * 32 + sl];
        float2 l = __half22float2(v.lo), h = __half22float2(v.hi);
        acc.x += l.x; acc.y += l.y; acc.z += h.x; acc.w += h.y;
    }
    // fold even/odd halves (identical column ranges)
    acc.x += __shfl_xor(acc.x, 32);
    acc.y += __shfl_xor(acc.y, 32);
    acc.z += __shfl_xor(acc.z, 32);
    acc.w += __shfl_xor(acc.w, 32);
    if (half == 0) {
        const float s = inv_in[node];
        const float4 bb = ((const float4*)b)[sl];
        float4 r;
        r.x = fmaxf(acc.x * s + bb.x, 0.f);
        r.y = fmaxf(acc.y * s + bb.y, 0.f);
        r.z = fmaxf(acc.z * s + bb.z, 0.f);
        r.w = fmaxf(acc.w * s + bb.w, 0.f);
        ((float4*)(out + (size_t)node * OS + off))[sl] = r;
    }
}

extern "C" void kernel_launch(void* const* d_in, const int* in_sizes, int n_in,
                              void* d_out, int out_size, void* d_ws, size_t ws_size,
                              hipStream_t stream) {
    const float* feat = (const float*)d_in[0];
    const float* W0 = (const float*)d_in[1];
    const float* b0 = (const float*)d_in[2];
    const float* W1 = (const float*)d_in[3];
    const float* b1 = (const float*)d_in[4];
    const float* W2 = (const float*)d_in[5];
    const float* b2 = (const float*)d_in[6];
    const int* src = (const int*)d_in[7];
    const int* dst = (const int*)d_in[8];
    float* out = (float*)d_out;
    float* ws = (float*)d_ws;

    __half* tmp = (__half*)ws;                    // NN*FD halves = 25.6MB
    int2* pairs = (int2*)(ws + (size_t)NN * 64);  // 12.8MB in the upper half of tmp region
    float* base2 = ws + (size_t)NN * 128;
    int* cnt_out = (int*)base2;                   // NN ints
    int* bktcnt = cnt_out + NN;                   // NBKT ints (contiguous with cnt_out for memset)
    int* bkt_base = bktcnt + NBKT;                // NBKT+1 ints
    int* bkt_cursor = bkt_base + NBKT + 1;        // NBKT ints
    float* inv = (float*)(bkt_cursor + NBKT);     // 2N floats (inv_out | inv_in)
    int* row_ptr = (int*)(inv + 2 * NN);          // N+1 ints
    int* col = row_ptr + NN + 1;                  // NE ints
    short* Wt = (short*)(col + NE);               // 3*FD*FD bf16

    hipMemsetAsync(cnt_out, 0, (NN + NBKT) * sizeof(int), stream);
    k_init_out<<<4096, 256, 0, stream>>>(feat, out);
    k_prep_w<<<(3 * FD * FD + 255) / 256, 256, 0, stream>>>(W0, W1, W2, Wt);
    k_deg<<<2048, 256, 0, stream>>>(src, dst, cnt_out, bktcnt);
    k_bkt_scan<<<1, 256, 0, stream>>>(bktcnt, bkt_base, bkt_cursor);
    k_part<<<(NE + PCH - 1) / PCH, 256, 0, stream>>>(src, dst, bkt_cursor, pairs);
    k_build<<<NBKT, 256, 0, stream>>>(pairs, bkt_base, row_ptr, col, inv + NN);
    k_invsqrt<<<(NN + 255) / 256, 256, 0, stream>>>(cnt_out, inv, NN);

    const float* bs[3] = {b0, b1, b2};
    const float* h = feat;
    int hstride = FD;
    for (int l = 0; l < 3; ++l) {
        k_gemm<<<(NN + 127) / 128, 256, 0, stream>>>(h, hstride, Wt + l * FD * FD, inv, tmp);
        k_gather<<<(NN + 3) / 4, 256, 0, stream>>>(tmp, row_ptr, col, inv + NN, bs[l], out,
                                                   FD * (l + 1));
        h = out + FD * (l + 1);
        hstride = OS;
    }
}

// Round 6
// 626.589 us; speedup vs baseline: 2.0639x; 1.0682x over previous
//
#include <hip/hip_runtime.h>
#include <hip/hip_fp16.h>

#define NN 100000
#define NE 1600000
#define FD 128
#define OS 512   // output row stride: [feat | h1 | h2 | h3]
#define LDA 136  // LDS row stride in bf16 elems (128 + 8 pad -> bank-conflict-free)
#define NBKT 196 // dst buckets of 512 nodes: (99999>>9)=195 -> 196 buckets
#define PCH 4096 // edges per block in partition pass

typedef __attribute__((ext_vector_type(8))) short short8;
typedef __attribute__((ext_vector_type(4))) float f32x4;

__device__ __forceinline__ short f2bf(float x) {
    unsigned u = __float_as_uint(x);
    u = (u + 0x7fff + ((u >> 16) & 1)) >> 16;   // round-to-nearest-even
    return (short)u;
}

// ---------------- init: copy feat into cols 0:128 of out ----------------
__global__ void k_init_out(const float* __restrict__ feat, float* __restrict__ out) {
    const size_t total = (size_t)NN * 32;  // float4s per feat row
    for (size_t i = (size_t)blockIdx.x * blockDim.x + threadIdx.x; i < total;
         i += (size_t)gridDim.x * blockDim.x) {
        size_t n = i >> 5;
        int c4 = (int)(i & 31);
        ((float4*)(out + n * OS))[c4] = ((const float4*)feat)[n * 32 + c4];
    }
}

// ---------------- prep: Wt[l][n][k] = bf16(W_l[k][n]) ----------------
__global__ void k_prep_w(const float* __restrict__ W0, const float* __restrict__ W1,
                         const float* __restrict__ W2, short* __restrict__ Wt) {
    int i = blockIdx.x * blockDim.x + threadIdx.x;
    if (i >= 3 * FD * FD) return;
    int l = i >> 14, r = i & (FD * FD - 1);
    int n = r >> 7, k = r & 127;
    const float* W = (l == 0) ? W0 : ((l == 1) ? W1 : W2);
    Wt[i] = f2bf(W[k * FD + n]);   // i = l*16384 + n*128 + k
}

// ---------------- degrees: out-degree atomics + dst-BUCKET histogram ----------
__global__ __launch_bounds__(256) void k_deg(const int* __restrict__ src,
                                             const int* __restrict__ dst,
                                             int* __restrict__ cnt_out,
                                             int* __restrict__ bktcnt) {
    __shared__ int h[NBKT];
    for (int i = threadIdx.x; i < NBKT; i += 256) h[i] = 0;
    __syncthreads();
    const int total4 = NE / 4;
    for (int i = blockIdx.x * blockDim.x + threadIdx.x; i < total4;
         i += gridDim.x * blockDim.x) {
        int4 s = ((const int4*)src)[i];
        int4 d = ((const int4*)dst)[i];
        atomicAdd(&cnt_out[s.x], 1); atomicAdd(&cnt_out[s.y], 1);
        atomicAdd(&cnt_out[s.z], 1); atomicAdd(&cnt_out[s.w], 1);
        atomicAdd(&h[d.x >> 9], 1); atomicAdd(&h[d.y >> 9], 1);
        atomicAdd(&h[d.z >> 9], 1); atomicAdd(&h[d.w >> 9], 1);
    }
    __syncthreads();
    for (int i = threadIdx.x; i < NBKT; i += 256)
        if (h[i]) atomicAdd(&bktcnt[i], h[i]);
}

__global__ void k_invsqrt(const int* __restrict__ cnt, float* __restrict__ inv, int n) {
    int i = blockIdx.x * blockDim.x + threadIdx.x;
    if (i < n) inv[i] = rsqrtf((float)max(cnt[i], 1));
}

// ---------------- scan of 196 bucket counts (1 block) ----------------
__global__ __launch_bounds__(256) void k_bkt_scan(const int* __restrict__ bktcnt,
                                                  int* __restrict__ bkt_base,
                                                  int* __restrict__ bkt_cursor) {
    __shared__ int s[256];
    const int tid = threadIdx.x;
    int v = (tid < NBKT) ? bktcnt[tid] : 0;
    s[tid] = v;
    __syncthreads();
    for (int off = 1; off < 256; off <<= 1) {
        int t = (tid >= off) ? s[tid - off] : 0;
        __syncthreads();
        s[tid] += t;
        __syncthreads();
    }
    int excl = s[tid] - v;
    if (tid < NBKT) { bkt_base[tid] = excl; bkt_cursor[tid] = excl; }
    if (tid == NBKT - 1) bkt_base[NBKT] = excl + v;   // == NE
}

// ---------------- P1: radix-partition edges into dst-buckets (pairs) ----------
__global__ __launch_bounds__(256) void k_part(const int* __restrict__ src,
                                              const int* __restrict__ dst,
                                              int* __restrict__ bkt_cursor,
                                              int2* __restrict__ pairs) {
    __shared__ int hist[NBKT];
    __shared__ int base[NBKT];
    __shared__ int lofs[NBKT];
    const int tid = threadIdx.x;
    const int e0 = blockIdx.x * PCH;
    for (int i = tid; i < NBKT; i += 256) { hist[i] = 0; lofs[i] = 0; }
    __syncthreads();
    int md[16], ms[16];
    #pragma unroll
    for (int k = 0; k < 16; ++k) {
        int e = e0 + k * 256 + tid;
        md[k] = (e < NE) ? dst[e] : -1;
        ms[k] = (e < NE) ? src[e] : 0;
    }
    #pragma unroll
    for (int k = 0; k < 16; ++k)
        if (md[k] >= 0) atomicAdd(&hist[md[k] >> 9], 1);
    __syncthreads();
    for (int i = tid; i < NBKT; i += 256)
        base[i] = hist[i] ? atomicAdd(&bkt_cursor[i], hist[i]) : 0;
    __syncthreads();
    #pragma unroll
    for (int k = 0; k < 16; ++k)
        if (md[k] >= 0) {
            int b = md[k] >> 9;
            int off = atomicAdd(&lofs[b], 1);
            pairs[base[b] + off] = make_int2(ms[k], md[k]);
        }
}

// ---------------- P2: per-bucket CSR build (LDS histogram + scan + place) ------
__global__ __launch_bounds__(256) void k_build(const int2* __restrict__ pairs,
                                               const int* __restrict__ bkt_base,
                                               int* __restrict__ row_ptr,
                                               int* __restrict__ col,
                                               float* __restrict__ inv_in) {
    __shared__ int cnt_s[512];
    __shared__ int wsum[4];
    const int b = blockIdx.x;
    const int tid = threadIdx.x;
    const int lane = tid & 63, wid = tid >> 6;
    const int ebeg = bkt_base[b], eend = bkt_base[b + 1];
    const int n0 = b << 9;
    cnt_s[tid] = 0; cnt_s[tid + 256] = 0;
    __syncthreads();
    for (int e = ebeg + tid; e < eend; e += 256)
        atomicAdd(&cnt_s[pairs[e].y - n0], 1);
    __syncthreads();
    const int v0 = cnt_s[2 * tid], v1 = cnt_s[2 * tid + 1];
    const int sum2 = v0 + v1;
    int incl = sum2;
    #pragma unroll
    for (int off = 1; off < 64; off <<= 1) {
        int t = __shfl_up(incl, off, 64);
        if (lane >= off) incl += t;
    }
    if (lane == 63) wsum[wid] = incl;
    __syncthreads();
    if (tid == 0) {
        int c = 0;
        #pragma unroll
        for (int i = 0; i < 4; ++i) { int t = wsum[i]; wsum[i] = c; c += t; }
    }
    __syncthreads();
    const int e0 = wsum[wid] + incl - sum2;
    cnt_s[2 * tid] = e0;
    cnt_s[2 * tid + 1] = e0 + v0;
    const int g0 = n0 + 2 * tid, g1 = g0 + 1;
    if (g0 < NN) { row_ptr[g0] = ebeg + e0; inv_in[g0] = rsqrtf((float)max(v0, 1)); }
    if (g1 < NN) { row_ptr[g1] = ebeg + e0 + v0; inv_in[g1] = rsqrtf((float)max(v1, 1)); }
    if (b == NBKT - 1 && tid == 0) row_ptr[NN] = eend;
    __syncthreads();
    for (int e = ebeg + tid; e < eend; e += 256) {
        int2 p = pairs[e];
        int pos = atomicAdd(&cnt_s[p.y - n0], 1);
        col[ebeg + pos] = p.x;
    }
}

// ---------------- MFMA GEMM -> int8 row-scaled tmp ----------------
// tmp8[r][col_p] int8 with per-row scale: v = scales[r] * q. Column PERMUTED:
// col_p = m*8 + ct  (orig col c = ct*16 + m) so each lane's 8 ct-bytes per row
// are contiguous -> one 8 B store per row per lane. Gather un-permutes at its
// once-per-node output write.
__global__ __launch_bounds__(256) void k_gemm(const float* __restrict__ h, int hstride,
                                              const short* __restrict__ Wt,
                                              const float* __restrict__ inv_out,
                                              unsigned char* __restrict__ tmp8,
                                              float* __restrict__ scales) {
    __shared__ short Ws[FD * LDA];   // Wt[n][k], padded rows: 34 KB
    __shared__ short hA[64 * LDA];   // h tile bf16, padded rows: 17 KB
    const int tid = threadIdx.x;
    for (int i = tid; i < FD * 16; i += 256) {   // 2048 chunks of 8 bf16
        int n = i >> 4, c = i & 15;
        short8 v = *(const short8*)(Wt + n * FD + c * 8);
        *(short8*)(&Ws[n * LDA + c * 8]) = v;
    }
    const int row0 = blockIdx.x * 128;
    const int wid = tid >> 6, lane = tid & 63;
    const int m = lane & 15, quad = lane >> 4;

    for (int sub = 0; sub < 2; ++sub) {
        const int rbase = row0 + sub * 64;
        __syncthreads();   // sub0: Ws staged; sub>0: prev compute done before hA overwrite
        for (int i = tid; i < 64 * 32; i += 256) {   // float4 chunks
            int r = i >> 5, c4 = i & 31;
            int gr = rbase + r;
            float4 v = make_float4(0.f, 0.f, 0.f, 0.f);
            if (gr < NN) v = ((const float4*)(h + (size_t)gr * hstride))[c4];
            short4 b;
            b.x = f2bf(v.x); b.y = f2bf(v.y); b.z = f2bf(v.z); b.w = f2bf(v.w);
            *(short4*)(&hA[r * LDA + c4 * 4]) = b;
        }
        __syncthreads();
        const int rtile = rbase + wid * 16;          // this wave's 16 rows
        short8 a0 = *(const short8*)(&hA[(wid * 16 + m) * LDA + 0 * 32 + quad * 8]);
        short8 a1 = *(const short8*)(&hA[(wid * 16 + m) * LDA + 1 * 32 + quad * 8]);
        short8 a2 = *(const short8*)(&hA[(wid * 16 + m) * LDA + 2 * 32 + quad * 8]);
        short8 a3 = *(const short8*)(&hA[(wid * 16 + m) * LDA + 3 * 32 + quad * 8]);
        float s0, s1, s2, s3;
        {
            int r = rtile + quad * 4;
            s0 = (r + 0 < NN) ? inv_out[r + 0] : 0.f;
            s1 = (r + 1 < NN) ? inv_out[r + 1] : 0.f;
            s2 = (r + 2 < NN) ? inv_out[r + 2] : 0.f;
            s3 = (r + 3 < NN) ? inv_out[r + 3] : 0.f;
        }
        // accumulate all 8 col-tiles (rows scaled by inv_out)
        f32x4 accs[8];
        #pragma unroll
        for (int ct = 0; ct < 8; ++ct) {
            f32x4 acc = {0.f, 0.f, 0.f, 0.f};
            short8 b0 = *(const short8*)(&Ws[(ct * 16 + m) * LDA + 0 * 32 + quad * 8]);
            short8 b1 = *(const short8*)(&Ws[(ct * 16 + m) * LDA + 1 * 32 + quad * 8]);
            short8 b2 = *(const short8*)(&Ws[(ct * 16 + m) * LDA + 2 * 32 + quad * 8]);
            short8 b3 = *(const short8*)(&Ws[(ct * 16 + m) * LDA + 3 * 32 + quad * 8]);
            acc = __builtin_amdgcn_mfma_f32_16x16x32_bf16(a0, b0, acc, 0, 0, 0);
            acc = __builtin_amdgcn_mfma_f32_16x16x32_bf16(a1, b1, acc, 0, 0, 0);
            acc = __builtin_amdgcn_mfma_f32_16x16x32_bf16(a2, b2, acc, 0, 0, 0);
            acc = __builtin_amdgcn_mfma_f32_16x16x32_bf16(a3, b3, acc, 0, 0, 0);
            acc[0] *= s0; acc[1] *= s1; acc[2] *= s2; acc[3] *= s3;
            accs[ct] = acc;
        }
        // per-row absmax over the 128 cols: max over ct (in-reg), then over the
        // 16 m-lanes of this quad (xor masks 1,2,4,8 stay inside the group)
        float pm0 = 0.f, pm1 = 0.f, pm2 = 0.f, pm3 = 0.f;
        #pragma unroll
        for (int ct = 0; ct < 8; ++ct) {
            pm0 = fmaxf(pm0, fabsf(accs[ct][0]));
            pm1 = fmaxf(pm1, fabsf(accs[ct][1]));
            pm2 = fmaxf(pm2, fabsf(accs[ct][2]));
            pm3 = fmaxf(pm3, fabsf(accs[ct][3]));
        }
        #pragma unroll
        for (int off = 1; off < 16; off <<= 1) {
            pm0 = fmaxf(pm0, __shfl_xor(pm0, off));
            pm1 = fmaxf(pm1, __shfl_xor(pm1, off));
            pm2 = fmaxf(pm2, __shfl_xor(pm2, off));
            pm3 = fmaxf(pm3, __shfl_xor(pm3, off));
        }
        const float is0 = pm0 > 0.f ? 127.f / pm0 : 0.f;
        const float is1 = pm1 > 0.f ? 127.f / pm1 : 0.f;
        const float is2 = pm2 > 0.f ? 127.f / pm2 : 0.f;
        const float is3 = pm3 > 0.f ? 127.f / pm3 : 0.f;
        const int r = rtile + quad * 4;
        if (m == 0) {
            const float inv127 = 1.f / 127.f;
            if (r + 3 < NN) {
                float4 sv = make_float4(pm0 * inv127, pm1 * inv127, pm2 * inv127, pm3 * inv127);
                *((float4*)(scales + r)) = sv;
            } else {
                if (r + 0 < NN) scales[r + 0] = pm0 * inv127;
                if (r + 1 < NN) scales[r + 1] = pm1 * inv127;
                if (r + 2 < NN) scales[r + 2] = pm2 * inv127;
                if (r + 3 < NN) scales[r + 3] = pm3 * inv127;
            }
        }
        // quantize + pack 8 ct-bytes per row -> one 8 B store per row
        unsigned long long w0 = 0ull, w1 = 0ull, w2 = 0ull, w3 = 0ull;
        #pragma unroll
        for (int ct = 0; ct < 8; ++ct) {
            unsigned char q0 = (unsigned char)(char)(int)rintf(accs[ct][0] * is0);
            unsigned char q1 = (unsigned char)(char)(int)rintf(accs[ct][1] * is1);
            unsigned char q2 = (unsigned char)(char)(int)rintf(accs[ct][2] * is2);
            unsigned char q3 = (unsigned char)(char)(int)rintf(accs[ct][3] * is3);
            w0 |= (unsigned long long)q0 << (8 * ct);
            w1 |= (unsigned long long)q1 << (8 * ct);
            w2 |= (unsigned long long)q2 << (8 * ct);
            w3 |= (unsigned long long)q3 << (8 * ct);
        }
        unsigned char* base = tmp8 + (size_t)r * FD + m * 8;
        if (r + 3 < NN) {
            *(unsigned long long*)(base + 0 * FD) = w0;
            *(unsigned long long*)(base + 1 * FD) = w1;
            *(unsigned long long*)(base + 2 * FD) = w2;
            *(unsigned long long*)(base + 3 * FD) = w3;
        } else {
            if (r + 0 < NN) *(unsigned long long*)(base + 0 * FD) = w0;
            if (r + 1 < NN) *(unsigned long long*)(base + 1 * FD) = w1;
            if (r + 2 < NN) *(unsigned long long*)(base + 2 * FD) = w2;
            if (r + 3 < NN) *(unsigned long long*)(base + 3 * FD) = w3;
        }
    }
}

// ---------------- gather: out[d][off:off+128] = relu(inv_in[d]*sum tmp[s] + b) ----
// tmp rows are 128 B int8 (2 cache lines/edge vs fp16's 4 -> halves the L3
// line-transaction count that bounds this kernel). scales[] is 400 KB ->
// L2-resident broadcast load, no extra L3 transactions. Columns stored
// permuted (col_p = m*8+ct); un-permute only at the per-node output write.
__global__ __launch_bounds__(256) void k_gather(const unsigned char* __restrict__ tmp8,
                                                const float* __restrict__ scales,
                                                const int* __restrict__ row_ptr,
                                                const int* __restrict__ col,
                                                const float* __restrict__ inv_in,
                                                const float* __restrict__ bias,
                                                float* __restrict__ out, int off) {
    const int wid = threadIdx.x >> 6;
    const int lane = threadIdx.x & 63;
    const int half = lane >> 5;   // 0: even edges, 1: odd edges
    const int sl = lane & 31;     // 4 B (4 cols) of the 128 B row per lane
    const int node = blockIdx.x * 4 + wid;
    if (node >= NN) return;
    const int beg = row_ptr[node], end = row_ptr[node + 1];
    float a0 = 0.f, a1 = 0.f, a2 = 0.f, a3 = 0.f;
    int j = beg + half;
    for (; j + 6 < end; j += 8) {   // 4 edges per half per iter -> 8/wave in flight
        int s0 = col[j], s1 = col[j + 2], s2 = col[j + 4], s3 = col[j + 6];
        char4 c0 = *(const char4*)(tmp8 + (size_t)s0 * FD + sl * 4);
        char4 c1 = *(const char4*)(tmp8 + (size_t)s1 * FD + sl * 4);
        char4 c2 = *(const char4*)(tmp8 + (size_t)s2 * FD + sl * 4);
        char4 c3 = *(const char4*)(tmp8 + (size_t)s3 * FD + sl * 4);
        float f0 = scales[s0], f1 = scales[s1], f2 = scales[s2], f3 = scales[s3];
        a0 += f0 * (float)c0.x + f1 * (float)c1.x + f2 * (float)c2.x + f3 * (float)c3.x;
        a1 += f0 * (float)c0.y + f1 * (float)c1.y + f2 * (float)c2.y + f3 * (float)c3.y;
        a2 += f0 * (float)c0.z + f1 * (float)c1.z + f2 * (float)c2.z + f3 * (float)c3.z;
        a3 += f0 * (float)c0.w + f1 * (float)c1.w + f2 * (float)c2.w + f3 * (float)c3.w;
    }
    for (; j < end; j += 2) {
        int s0 = col[j];
        char4 c0 = *(const char4*)(tmp8 + (size_t)s0 * FD + sl * 4);
        float f0 = scales[s0];
        a0 += f0 * (float)c0.x;
        a1 += f0 * (float)c0.y;
        a2 += f0 * (float)c0.z;
        a3 += f0 * (float)c0.w;
    }
    // fold even/odd halves (identical column ranges)
    a0 += __shfl_xor(a0, 32);
    a1 += __shfl_xor(a1, 32);
    a2 += __shfl_xor(a2, 32);
    a3 += __shfl_xor(a3, 32);
    if (half == 0) {
        const float s = inv_in[node];
        float* ob = out + (size_t)node * OS + off;
        float av[4] = {a0, a1, a2, a3};
        #pragma unroll
        for (int k = 0; k < 4; ++k) {
            int jj = 4 * sl + k;                 // permuted col index
            int c = ((jj & 7) << 4) + (jj >> 3); // original col
            ob[c] = fmaxf(av[k] * s + bias[c], 0.f);
        }
    }
}

extern "C" void kernel_launch(void* const* d_in, const int* in_sizes, int n_in,
                              void* d_out, int out_size, void* d_ws, size_t ws_size,
                              hipStream_t stream) {
    const float* feat = (const float*)d_in[0];
    const float* W0 = (const float*)d_in[1];
    const float* b0 = (const float*)d_in[2];
    const float* W1 = (const float*)d_in[3];
    const float* b1 = (const float*)d_in[4];
    const float* W2 = (const float*)d_in[5];
    const float* b2 = (const float*)d_in[6];
    const int* src = (const int*)d_in[7];
    const int* dst = (const int*)d_in[8];
    float* out = (float*)d_out;
    float* ws = (float*)d_ws;

    unsigned char* tmp8 = (unsigned char*)ws;     // NN*128 int8 = 12.8 MB
    int2* pairs = (int2*)(ws + (size_t)NN * 64);  // 12.8 MB at 25.6 MB offset
    float* scales = ws + (size_t)NN * 96;         // 400 KB at 38.4 MB offset
    float* base2 = ws + (size_t)NN * 128;         // pre-pass region (unchanged)
    int* cnt_out = (int*)base2;                   // NN ints
    int* bktcnt = cnt_out + NN;                   // NBKT ints
    int* bkt_base = bktcnt + NBKT;                // NBKT+1 ints
    int* bkt_cursor = bkt_base + NBKT + 1;        // NBKT ints
    float* inv = (float*)(bkt_cursor + NBKT);     // 2N floats (inv_out | inv_in)
    int* row_ptr = (int*)(inv + 2 * NN);          // N+1 ints
    int* col = row_ptr + NN + 1;                  // NE ints
    short* Wt = (short*)(col + NE);               // 3*FD*FD bf16

    hipMemsetAsync(cnt_out, 0, (NN + NBKT) * sizeof(int), stream);
    k_init_out<<<4096, 256, 0, stream>>>(feat, out);
    k_prep_w<<<(3 * FD * FD + 255) / 256, 256, 0, stream>>>(W0, W1, W2, Wt);
    k_deg<<<2048, 256, 0, stream>>>(src, dst, cnt_out, bktcnt);
    k_bkt_scan<<<1, 256, 0, stream>>>(bktcnt, bkt_base, bkt_cursor);
    k_part<<<(NE + PCH - 1) / PCH, 256, 0, stream>>>(src, dst, bkt_cursor, pairs);
    k_build<<<NBKT, 256, 0, stream>>>(pairs, bkt_base, row_ptr, col, inv + NN);
    k_invsqrt<<<(NN + 255) / 256, 256, 0, stream>>>(cnt_out, inv, NN);

    const float* bs[3] = {b0, b1, b2};
    const float* h = feat;
    int hstride = FD;
    for (int l = 0; l < 3; ++l) {
        k_gemm<<<(NN + 127) / 128, 256, 0, stream>>>(h, hstride, Wt + l * FD * FD, inv,
                                                     tmp8, scales);
        k_gather<<<(NN + 3) / 4, 256, 0, stream>>>(tmp8, scales, row_ptr, col, inv + NN,
                                                   bs[l], out, FD * (l + 1));
        h = out + FD * (l + 1);
        hstride = OS;
    }
}

// Round 7
// 566.048 us; speedup vs baseline: 2.2846x; 1.1070x over previous
//
#include <hip/hip_runtime.h>
#include <hip/hip_fp16.h>

#define NN 100000
#define NE 1600000
#define FD 128
#define OS 512   // output row stride: [feat | h1 | h2 | h3]
#define LDA 136  // LDS row stride in bf16 elems (128 + 8 pad -> bank-conflict-free)
#define NBKT 196 // buckets of 512 nodes: (99999>>9)=195 -> 196 buckets
#define PCH 4096 // edges per block in partition pass

typedef __attribute__((ext_vector_type(8))) short short8;
typedef __attribute__((ext_vector_type(4))) float f32x4;

__device__ __forceinline__ short f2bf(float x) {
    unsigned u = __float_as_uint(x);
    u = (u + 0x7fff + ((u >> 16) & 1)) >> 16;   // round-to-nearest-even
    return (short)u;
}

// ---------------- init: copy feat into cols 0:128 of out ----------------
__global__ void k_init_out(const float* __restrict__ feat, float* __restrict__ out) {
    const size_t total = (size_t)NN * 32;  // float4s per feat row
    for (size_t i = (size_t)blockIdx.x * blockDim.x + threadIdx.x; i < total;
         i += (size_t)gridDim.x * blockDim.x) {
        size_t n = i >> 5;
        int c4 = (int)(i & 31);
        ((float4*)(out + n * OS))[c4] = ((const float4*)feat)[n * 32 + c4];
    }
}

// ---------------- prep: Wt[l][n][k] = bf16(W_l[k][n]) ----------------
__global__ void k_prep_w(const float* __restrict__ W0, const float* __restrict__ W1,
                         const float* __restrict__ W2, short* __restrict__ Wt) {
    int i = blockIdx.x * blockDim.x + threadIdx.x;
    if (i >= 3 * FD * FD) return;
    int l = i >> 14, r = i & (FD * FD - 1);
    int n = r >> 7, k = r & 127;
    const float* W = (l == 0) ? W0 : ((l == 1) ? W1 : W2);
    Wt[i] = f2bf(W[k * FD + n]);   // i = l*16384 + n*128 + k
}

// ---------------- bucket histograms of src AND dst (no global random atomics) --
__global__ __launch_bounds__(256) void k_deg(const int* __restrict__ src,
                                             const int* __restrict__ dst,
                                             int* __restrict__ bktcnt_d,
                                             int* __restrict__ bktcnt_s) {
    __shared__ int hd[NBKT];
    __shared__ int hs[NBKT];
    for (int i = threadIdx.x; i < NBKT; i += 256) { hd[i] = 0; hs[i] = 0; }
    __syncthreads();
    const int total4 = NE / 4;
    for (int i = blockIdx.x * blockDim.x + threadIdx.x; i < total4;
         i += gridDim.x * blockDim.x) {
        int4 s = ((const int4*)src)[i];
        int4 d = ((const int4*)dst)[i];
        atomicAdd(&hs[s.x >> 9], 1); atomicAdd(&hs[s.y >> 9], 1);
        atomicAdd(&hs[s.z >> 9], 1); atomicAdd(&hs[s.w >> 9], 1);
        atomicAdd(&hd[d.x >> 9], 1); atomicAdd(&hd[d.y >> 9], 1);
        atomicAdd(&hd[d.z >> 9], 1); atomicAdd(&hd[d.w >> 9], 1);
    }
    __syncthreads();
    for (int i = threadIdx.x; i < NBKT; i += 256) {
        if (hd[i]) atomicAdd(&bktcnt_d[i], hd[i]);
        if (hs[i]) atomicAdd(&bktcnt_s[i], hs[i]);
    }
}

// ---------------- scans of both 196-bucket count arrays (1 block) ----------------
__global__ __launch_bounds__(256) void k_scan2(const int* __restrict__ bktcnt_d,
                                               const int* __restrict__ bktcnt_s,
                                               int* __restrict__ base_d,
                                               int* __restrict__ cur_d,
                                               int* __restrict__ base_s,
                                               int* __restrict__ cur_s) {
    __shared__ int sh[256];
    const int tid = threadIdx.x;
    int v = (tid < NBKT) ? bktcnt_d[tid] : 0;
    sh[tid] = v;
    __syncthreads();
    for (int off = 1; off < 256; off <<= 1) {
        int t = (tid >= off) ? sh[tid - off] : 0;
        __syncthreads();
        sh[tid] += t;
        __syncthreads();
    }
    int excl = sh[tid] - v;
    if (tid < NBKT) { base_d[tid] = excl; cur_d[tid] = excl; }
    if (tid == NBKT - 1) base_d[NBKT] = excl + v;   // == NE
    __syncthreads();
    v = (tid < NBKT) ? bktcnt_s[tid] : 0;
    sh[tid] = v;
    __syncthreads();
    for (int off = 1; off < 256; off <<= 1) {
        int t = (tid >= off) ? sh[tid - off] : 0;
        __syncthreads();
        sh[tid] += t;
        __syncthreads();
    }
    excl = sh[tid] - v;
    if (tid < NBKT) { base_s[tid] = excl; cur_s[tid] = excl; }
    if (tid == NBKT - 1) base_s[NBKT] = excl + v;   // == NE
}

// ---------------- P1: dual radix-partition (dst -> pairs, src -> local-id stream)
__global__ __launch_bounds__(256) void k_part(const int* __restrict__ src,
                                              const int* __restrict__ dst,
                                              int* __restrict__ cur_d,
                                              int* __restrict__ cur_s,
                                              int2* __restrict__ pairs,
                                              unsigned short* __restrict__ ssrc) {
    __shared__ int hd[NBKT], bd[NBKT], ld_[NBKT];
    __shared__ int hs_[NBKT], bs_[NBKT], ls_[NBKT];
    const int tid = threadIdx.x;
    const int e0 = blockIdx.x * PCH;
    for (int i = tid; i < NBKT; i += 256) { hd[i] = 0; ld_[i] = 0; hs_[i] = 0; ls_[i] = 0; }
    __syncthreads();
    int md[16], ms[16];
    #pragma unroll
    for (int k = 0; k < 16; ++k) {
        int e = e0 + k * 256 + tid;
        md[k] = (e < NE) ? dst[e] : -1;
        ms[k] = (e < NE) ? src[e] : -1;
    }
    #pragma unroll
    for (int k = 0; k < 16; ++k)
        if (md[k] >= 0) {
            atomicAdd(&hd[md[k] >> 9], 1);
            atomicAdd(&hs_[ms[k] >> 9], 1);
        }
    __syncthreads();
    for (int i = tid; i < NBKT; i += 256) {
        bd[i] = hd[i] ? atomicAdd(&cur_d[i], hd[i]) : 0;
        bs_[i] = hs_[i] ? atomicAdd(&cur_s[i], hs_[i]) : 0;
    }
    __syncthreads();
    #pragma unroll
    for (int k = 0; k < 16; ++k)
        if (md[k] >= 0) {
            int b = md[k] >> 9;
            int off = atomicAdd(&ld_[b], 1);
            pairs[bd[b] + off] = make_int2(ms[k], md[k]);
            int b2 = ms[k] >> 9;
            int off2 = atomicAdd(&ls_[b2], 1);
            ssrc[bs_[b2] + off2] = (unsigned short)(ms[k] & 511);
        }
}

// ---------------- P2: per-bucket CSR build (LDS histogram + scan + place) ------
__global__ __launch_bounds__(256) void k_build(const int2* __restrict__ pairs,
                                               const int* __restrict__ bkt_base,
                                               int* __restrict__ row_ptr,
                                               int* __restrict__ col,
                                               float* __restrict__ inv_in) {
    __shared__ int cnt_s[512];
    __shared__ int wsum[4];
    const int b = blockIdx.x;
    const int tid = threadIdx.x;
    const int lane = tid & 63, wid = tid >> 6;
    const int ebeg = bkt_base[b], eend = bkt_base[b + 1];
    const int n0 = b << 9;
    cnt_s[tid] = 0; cnt_s[tid + 256] = 0;
    __syncthreads();
    for (int e = ebeg + tid; e < eend; e += 256)
        atomicAdd(&cnt_s[pairs[e].y - n0], 1);
    __syncthreads();
    const int v0 = cnt_s[2 * tid], v1 = cnt_s[2 * tid + 1];
    const int sum2 = v0 + v1;
    int incl = sum2;
    #pragma unroll
    for (int off = 1; off < 64; off <<= 1) {
        int t = __shfl_up(incl, off, 64);
        if (lane >= off) incl += t;
    }
    if (lane == 63) wsum[wid] = incl;
    __syncthreads();
    if (tid == 0) {
        int c = 0;
        #pragma unroll
        for (int i = 0; i < 4; ++i) { int t = wsum[i]; wsum[i] = c; c += t; }
    }
    __syncthreads();
    const int e0 = wsum[wid] + incl - sum2;
    cnt_s[2 * tid] = e0;
    cnt_s[2 * tid + 1] = e0 + v0;
    const int g0 = n0 + 2 * tid, g1 = g0 + 1;
    if (g0 < NN) { row_ptr[g0] = ebeg + e0; inv_in[g0] = rsqrtf((float)max(v0, 1)); }
    if (g1 < NN) { row_ptr[g1] = ebeg + e0 + v0; inv_in[g1] = rsqrtf((float)max(v1, 1)); }
    if (b == NBKT - 1 && tid == 0) row_ptr[NN] = eend;
    __syncthreads();
    for (int e = ebeg + tid; e < eend; e += 256) {
        int2 p = pairs[e];
        int pos = atomicAdd(&cnt_s[p.y - n0], 1);
        col[ebeg + pos] = p.x;
    }
}

// ---------------- P3: per-bucket out-degree -> inv_out (no global atomics) -----
__global__ __launch_bounds__(256) void k_build_src(const unsigned short* __restrict__ ssrc,
                                                   const int* __restrict__ base_s,
                                                   float* __restrict__ inv_out) {
    __shared__ int cnt_s[512];
    const int b = blockIdx.x;
    const int tid = threadIdx.x;
    const int ebeg = base_s[b], eend = base_s[b + 1];
    cnt_s[tid] = 0; cnt_s[tid + 256] = 0;
    __syncthreads();
    for (int e = ebeg + tid; e < eend; e += 256)
        atomicAdd(&cnt_s[ssrc[e]], 1);
    __syncthreads();
    const int n0 = b << 9;
    const int g0 = n0 + tid, g1 = g0 + 256;
    if (g0 < NN) inv_out[g0] = rsqrtf((float)max(cnt_s[tid], 1));
    if (g1 < NN) inv_out[g1] = rsqrtf((float)max(cnt_s[tid + 256], 1));
}

// ---------------- MFMA GEMM -> int8 row-scaled tmp ----------------
// tmp8[r][col_p] int8 with per-row scale: v = scales[r] * q. Column PERMUTED:
// col_p = m*8 + ct (orig col c = ct*16 + m) -> one 8 B store per row per lane.
__global__ __launch_bounds__(256) void k_gemm(const float* __restrict__ h, int hstride,
                                              const short* __restrict__ Wt,
                                              const float* __restrict__ inv_out,
                                              unsigned char* __restrict__ tmp8,
                                              float* __restrict__ scales) {
    __shared__ short Ws[FD * LDA];   // Wt[n][k], padded rows: 34 KB
    __shared__ short hA[64 * LDA];   // h tile bf16, padded rows: 17 KB
    const int tid = threadIdx.x;
    for (int i = tid; i < FD * 16; i += 256) {   // 2048 chunks of 8 bf16
        int n = i >> 4, c = i & 15;
        short8 v = *(const short8*)(Wt + n * FD + c * 8);
        *(short8*)(&Ws[n * LDA + c * 8]) = v;
    }
    const int row0 = blockIdx.x * 128;
    const int wid = tid >> 6, lane = tid & 63;
    const int m = lane & 15, quad = lane >> 4;

    for (int sub = 0; sub < 2; ++sub) {
        const int rbase = row0 + sub * 64;
        __syncthreads();   // sub0: Ws staged; sub>0: prev compute done before hA overwrite
        for (int i = tid; i < 64 * 32; i += 256) {   // float4 chunks
            int r = i >> 5, c4 = i & 31;
            int gr = rbase + r;
            float4 v = make_float4(0.f, 0.f, 0.f, 0.f);
            if (gr < NN) v = ((const float4*)(h + (size_t)gr * hstride))[c4];
            short4 b;
            b.x = f2bf(v.x); b.y = f2bf(v.y); b.z = f2bf(v.z); b.w = f2bf(v.w);
            *(short4*)(&hA[r * LDA + c4 * 4]) = b;
        }
        __syncthreads();
        const int rtile = rbase + wid * 16;          // this wave's 16 rows
        short8 a0 = *(const short8*)(&hA[(wid * 16 + m) * LDA + 0 * 32 + quad * 8]);
        short8 a1 = *(const short8*)(&hA[(wid * 16 + m) * LDA + 1 * 32 + quad * 8]);
        short8 a2 = *(const short8*)(&hA[(wid * 16 + m) * LDA + 2 * 32 + quad * 8]);
        short8 a3 = *(const short8*)(&hA[(wid * 16 + m) * LDA + 3 * 32 + quad * 8]);
        float s0, s1, s2, s3;
        {
            int r = rtile + quad * 4;
            s0 = (r + 0 < NN) ? inv_out[r + 0] : 0.f;
            s1 = (r + 1 < NN) ? inv_out[r + 1] : 0.f;
            s2 = (r + 2 < NN) ? inv_out[r + 2] : 0.f;
            s3 = (r + 3 < NN) ? inv_out[r + 3] : 0.f;
        }
        f32x4 accs[8];
        #pragma unroll
        for (int ct = 0; ct < 8; ++ct) {
            f32x4 acc = {0.f, 0.f, 0.f, 0.f};
            short8 b0 = *(const short8*)(&Ws[(ct * 16 + m) * LDA + 0 * 32 + quad * 8]);
            short8 b1 = *(const short8*)(&Ws[(ct * 16 + m) * LDA + 1 * 32 + quad * 8]);
            short8 b2 = *(const short8*)(&Ws[(ct * 16 + m) * LDA + 2 * 32 + quad * 8]);
            short8 b3 = *(const short8*)(&Ws[(ct * 16 + m) * LDA + 3 * 32 + quad * 8]);
            acc = __builtin_amdgcn_mfma_f32_16x16x32_bf16(a0, b0, acc, 0, 0, 0);
            acc = __builtin_amdgcn_mfma_f32_16x16x32_bf16(a1, b1, acc, 0, 0, 0);
            acc = __builtin_amdgcn_mfma_f32_16x16x32_bf16(a2, b2, acc, 0, 0, 0);
            acc = __builtin_amdgcn_mfma_f32_16x16x32_bf16(a3, b3, acc, 0, 0, 0);
            acc[0] *= s0; acc[1] *= s1; acc[2] *= s2; acc[3] *= s3;
            accs[ct] = acc;
        }
        float pm0 = 0.f, pm1 = 0.f, pm2 = 0.f, pm3 = 0.f;
        #pragma unroll
        for (int ct = 0; ct < 8; ++ct) {
            pm0 = fmaxf(pm0, fabsf(accs[ct][0]));
            pm1 = fmaxf(pm1, fabsf(accs[ct][1]));
            pm2 = fmaxf(pm2, fabsf(accs[ct][2]));
            pm3 = fmaxf(pm3, fabsf(accs[ct][3]));
        }
        #pragma unroll
        for (int off = 1; off < 16; off <<= 1) {
            pm0 = fmaxf(pm0, __shfl_xor(pm0, off));
            pm1 = fmaxf(pm1, __shfl_xor(pm1, off));
            pm2 = fmaxf(pm2, __shfl_xor(pm2, off));
            pm3 = fmaxf(pm3, __shfl_xor(pm3, off));
        }
        const float is0 = pm0 > 0.f ? 127.f / pm0 : 0.f;
        const float is1 = pm1 > 0.f ? 127.f / pm1 : 0.f;
        const float is2 = pm2 > 0.f ? 127.f / pm2 : 0.f;
        const float is3 = pm3 > 0.f ? 127.f / pm3 : 0.f;
        const int r = rtile + quad * 4;
        if (m == 0) {
            const float inv127 = 1.f / 127.f;
            if (r + 3 < NN) {
                float4 sv = make_float4(pm0 * inv127, pm1 * inv127, pm2 * inv127, pm3 * inv127);
                *((float4*)(scales + r)) = sv;
            } else {
                if (r + 0 < NN) scales[r + 0] = pm0 * inv127;
                if (r + 1 < NN) scales[r + 1] = pm1 * inv127;
                if (r + 2 < NN) scales[r + 2] = pm2 * inv127;
                if (r + 3 < NN) scales[r + 3] = pm3 * inv127;
            }
        }
        unsigned long long w0 = 0ull, w1 = 0ull, w2 = 0ull, w3 = 0ull;
        #pragma unroll
        for (int ct = 0; ct < 8; ++ct) {
            unsigned char q0 = (unsigned char)(char)(int)rintf(accs[ct][0] * is0);
            unsigned char q1 = (unsigned char)(char)(int)rintf(accs[ct][1] * is1);
            unsigned char q2 = (unsigned char)(char)(int)rintf(accs[ct][2] * is2);
            unsigned char q3 = (unsigned char)(char)(int)rintf(accs[ct][3] * is3);
            w0 |= (unsigned long long)q0 << (8 * ct);
            w1 |= (unsigned long long)q1 << (8 * ct);
            w2 |= (unsigned long long)q2 << (8 * ct);
            w3 |= (unsigned long long)q3 << (8 * ct);
        }
        unsigned char* base = tmp8 + (size_t)r * FD + m * 8;
        if (r + 3 < NN) {
            *(unsigned long long*)(base + 0 * FD) = w0;
            *(unsigned long long*)(base + 1 * FD) = w1;
            *(unsigned long long*)(base + 2 * FD) = w2;
            *(unsigned long long*)(base + 3 * FD) = w3;
        } else {
            if (r + 0 < NN) *(unsigned long long*)(base + 0 * FD) = w0;
            if (r + 1 < NN) *(unsigned long long*)(base + 1 * FD) = w1;
            if (r + 2 < NN) *(unsigned long long*)(base + 2 * FD) = w2;
            if (r + 3 < NN) *(unsigned long long*)(base + 3 * FD) = w3;
        }
    }
}

// ---------------- gather: out[d][off:off+128] = relu(inv_in[d]*sum tmp[s] + b) ----
// 128 B int8 rows; per-node epilogue un-permutes through a 2 KB LDS restage so
// the global write is 32 coalesced float4 stores (was 128 scalar stores).
__global__ __launch_bounds__(256) void k_gather(const unsigned char* __restrict__ tmp8,
                                                const float* __restrict__ scales,
                                                const int* __restrict__ row_ptr,
                                                const int* __restrict__ col,
                                                const float* __restrict__ inv_in,
                                                const float* __restrict__ bias,
                                                float* __restrict__ out, int off) {
    __shared__ float ob_s[4][128];
    const int wid = threadIdx.x >> 6;
    const int lane = threadIdx.x & 63;
    const int half = lane >> 5;   // 0: even edges, 1: odd edges
    const int sl = lane & 31;     // 4 B (4 permuted cols) of the 128 B row per lane
    const int node = blockIdx.x * 4 + wid;
    if (node >= NN) return;
    const int beg = row_ptr[node], end = row_ptr[node + 1];
    float a0 = 0.f, a1 = 0.f, a2 = 0.f, a3 = 0.f;
    int j = beg + half;
    for (; j + 6 < end; j += 8) {   // 4 edges per half per iter -> 8/wave in flight
        int s0 = col[j], s1 = col[j + 2], s2 = col[j + 4], s3 = col[j + 6];
        char4 c0 = *(const char4*)(tmp8 + (size_t)s0 * FD + sl * 4);
        char4 c1 = *(const char4*)(tmp8 + (size_t)s1 * FD + sl * 4);
        char4 c2 = *(const char4*)(tmp8 + (size_t)s2 * FD + sl * 4);
        char4 c3 = *(const char4*)(tmp8 + (size_t)s3 * FD + sl * 4);
        float f0 = scales[s0], f1 = scales[s1], f2 = scales[s2], f3 = scales[s3];
        a0 += f0 * (float)c0.x + f1 * (float)c1.x + f2 * (float)c2.x + f3 * (float)c3.x;
        a1 += f0 * (float)c0.y + f1 * (float)c1.y + f2 * (float)c2.y + f3 * (float)c3.y;
        a2 += f0 * (float)c0.z + f1 * (float)c1.z + f2 * (float)c2.z + f3 * (float)c3.z;
        a3 += f0 * (float)c0.w + f1 * (float)c1.w + f2 * (float)c2.w + f3 * (float)c3.w;
    }
    for (; j < end; j += 2) {
        int s0 = col[j];
        char4 c0 = *(const char4*)(tmp8 + (size_t)s0 * FD + sl * 4);
        float f0 = scales[s0];
        a0 += f0 * (float)c0.x;
        a1 += f0 * (float)c0.y;
        a2 += f0 * (float)c0.z;
        a3 += f0 * (float)c0.w;
    }
    // fold even/odd halves (identical column ranges) -> both halves hold totals
    a0 += __shfl_xor(a0, 32);
    a1 += __shfl_xor(a1, 32);
    a2 += __shfl_xor(a2, 32);
    a3 += __shfl_xor(a3, 32);
    if (half == 0) {
        // un-permute via LDS (wave-local; per-wave DS ops complete in order)
        float av[4] = {a0, a1, a2, a3};
        #pragma unroll
        for (int k = 0; k < 4; ++k) {
            int jj = 4 * sl + k;                 // permuted col index
            int c = ((jj & 7) << 4) + (jj >> 3); // original col
            ob_s[wid][c] = av[k];
        }
        const float s = inv_in[node];
        float4 f4 = ((const float4*)ob_s[wid])[sl];
        const float4 bb = ((const float4*)bias)[sl];
        float4 r;
        r.x = fmaxf(f4.x * s + bb.x, 0.f);
        r.y = fmaxf(f4.y * s + bb.y, 0.f);
        r.z = fmaxf(f4.z * s + bb.z, 0.f);
        r.w = fmaxf(f4.w * s + bb.w, 0.f);
        ((float4*)(out + (size_t)node * OS + off))[sl] = r;
    }
}

extern "C" void kernel_launch(void* const* d_in, const int* in_sizes, int n_in,
                              void* d_out, int out_size, void* d_ws, size_t ws_size,
                              hipStream_t stream) {
    const float* feat = (const float*)d_in[0];
    const float* W0 = (const float*)d_in[1];
    const float* b0 = (const float*)d_in[2];
    const float* W1 = (const float*)d_in[3];
    const float* b1 = (const float*)d_in[4];
    const float* W2 = (const float*)d_in[5];
    const float* b2 = (const float*)d_in[6];
    const int* src = (const int*)d_in[7];
    const int* dst = (const int*)d_in[8];
    float* out = (float*)d_out;
    float* ws = (float*)d_ws;

    unsigned char* tmp8 = (unsigned char*)ws;          // NN*128 int8 = 12.8 MB
    int2* pairs = (int2*)(ws + (size_t)NN * 64);       // 12.8 MB at 25.6 MB offset
    float* scales = ws + (size_t)NN * 96;              // 400 KB at 38.4 MB offset
    unsigned short* ssrc = (unsigned short*)(ws + (size_t)NN * 104);  // NE u16 = 3.2 MB
    int* base2 = (int*)(ws + (size_t)NN * 128);        // pre-pass region
    int* bktcnt_d = base2;                             // NBKT
    int* bktcnt_s = bktcnt_d + NBKT;                   // NBKT (contiguous for memset)
    int* base_d = bktcnt_s + NBKT;                     // NBKT+1
    int* cur_d = base_d + NBKT + 1;                    // NBKT
    int* base_s = cur_d + NBKT;                        // NBKT+1
    int* cur_s = base_s + NBKT + 1;                    // NBKT
    float* inv = (float*)(cur_s + NBKT);               // 2N floats (inv_out | inv_in)
    int* row_ptr = (int*)(inv + 2 * NN);               // N+1
    int* col = row_ptr + NN + 1;                       // NE
    short* Wt = (short*)(col + NE);                    // 3*FD*FD bf16

    hipMemsetAsync(bktcnt_d, 0, 2 * NBKT * sizeof(int), stream);
    k_init_out<<<4096, 256, 0, stream>>>(feat, out);
    k_prep_w<<<(3 * FD * FD + 255) / 256, 256, 0, stream>>>(W0, W1, W2, Wt);
    k_deg<<<512, 256, 0, stream>>>(src, dst, bktcnt_d, bktcnt_s);
    k_scan2<<<1, 256, 0, stream>>>(bktcnt_d, bktcnt_s, base_d, cur_d, base_s, cur_s);
    k_part<<<(NE + PCH - 1) / PCH, 256, 0, stream>>>(src, dst, cur_d, cur_s, pairs, ssrc);
    k_build<<<NBKT, 256, 0, stream>>>(pairs, base_d, row_ptr, col, inv + NN);
    k_build_src<<<NBKT, 256, 0, stream>>>(ssrc, base_s, inv);

    const float* bs[3] = {b0, b1, b2};
    const float* h = feat;
    int hstride = FD;
    for (int l = 0; l < 3; ++l) {
        k_gemm<<<(NN + 127) / 128, 256, 0, stream>>>(h, hstride, Wt + l * FD * FD, inv,
                                                     tmp8, scales);
        k_gather<<<(NN + 3) / 4, 256, 0, stream>>>(tmp8, scales, row_ptr, col, inv + NN,
                                                   bs[l], out, FD * (l + 1));
        h = out + FD * (l + 1);
        hstride = OS;
    }
}